// Round 6
// baseline (301.581 us; speedup 1.0000x reference)
//
#include <hip/hip_runtime.h>
#include <stdint.h>

#define B_DIM 4
#define L_DIM 512
#define D_DIM 768
#define S_DIM 4096
#define DFF_DIM 3072
#define M_DIM (B_DIM * S_DIM)   // 16384

typedef unsigned short ushort_t;
typedef __attribute__((ext_vector_type(8))) short short8;
typedef __attribute__((ext_vector_type(4))) short short4v;
typedef __attribute__((ext_vector_type(4))) float floatx4;

// round-to-nearest-even fp32 -> bf16 bits
__device__ __forceinline__ ushort_t f2bf(float x) {
  unsigned int u = __float_as_uint(x);
  u += 0x7FFFu + ((u >> 16) & 1u);
  return (ushort_t)(u >> 16);
}

// async 16B global->LDS (lane-contiguous dest)
__device__ __forceinline__ void load_lds16(const ushort_t* g, ushort_t* lds) {
  __builtin_amdgcn_global_load_lds(
      (const __attribute__((address_space(1))) unsigned int*)g,
      (__attribute__((address_space(3))) unsigned int*)lds, 16, 0, 0);
}

// single-barrier phase fence (no memory clobber -> no compiler vmcnt drain)
#define PIN() __builtin_amdgcn_sched_barrier(0)
#define BAR()                                  \
  do {                                         \
    PIN();                                     \
    __builtin_amdgcn_s_barrier();              \
    PIN();                                     \
  } while (0)
#define WAIT_LGKM0()                           \
  do {                                         \
    asm volatile("s_waitcnt lgkmcnt(0)");      \
    PIN();                                     \
  } while (0)
#define WAIT_VM(n)                             \
  do {                                         \
    asm volatile("s_waitcnt vmcnt(" #n ")");   \
    PIN();                                     \
  } while (0)

// ---------------------------------------------------------------------------
// scan: P[b][l][d] = sum_{p<=l} h[b][p][d]  (fp32). 3072 independent chains,
// one per (b,d); lanes own consecutive d -> coalesced 256B per load instr.
// 8-unrolled so the 8 loads of a group are issued before the adds (latency
// hiding). 12 blocks x 256 threads; ~6 MB traffic.
// ---------------------------------------------------------------------------
__global__ __launch_bounds__(256)
void scan(const float* __restrict__ h, float* __restrict__ P) {
  const int g = blockIdx.x * 256 + threadIdx.x;  // 0..3071
  const int b = g / D_DIM;
  const int d = g - b * D_DIM;
  const float* src = h + (long)b * L_DIM * D_DIM + d;
  float* dst = P + (long)b * L_DIM * D_DIM + d;
  float run = 0.0f;
  for (int l = 0; l < L_DIM; l += 8) {
    float v[8];
#pragma unroll
    for (int u = 0; u < 8; ++u) v[u] = src[(long)(l + u) * D_DIM];
#pragma unroll
    for (int u = 0; u < 8; ++u) {
      run += v[u];
      dst[(long)(l + u) * D_DIM] = run;
    }
  }
}

// ---------------------------------------------------------------------------
// Fused prep: W1 transpose | W2 transpose | span mean via prefix table.
// span: mean = (P[end] - P[start-1]) * inv -- 6 float4 loads, no loop.
// ---------------------------------------------------------------------------
__device__ __forceinline__ void transpose_body(const float* __restrict__ in,
                                               ushort_t* __restrict__ out,
                                               int K, int N, int kb, int nb) {
  __shared__ float tile[32][33];
  const int k0 = kb * 32;
  const int n0 = nb * 32;
  const int tx = threadIdx.x & 31;
  const int ty = threadIdx.x >> 5;  // 0..7
#pragma unroll
  for (int r = 0; r < 32; r += 8)
    tile[ty + r][tx] = in[(long)(k0 + ty + r) * N + n0 + tx];
  __syncthreads();
#pragma unroll
  for (int r = 0; r < 32; r += 8)
    out[(long)(n0 + ty + r) * K + k0 + tx] = f2bf(tile[tx][ty + r]);
}

__device__ __forceinline__ void span_body(const float* __restrict__ P,
                                          const int* __restrict__ span_idx,
                                          ushort_t* __restrict__ A, int blk) {
  const int wave = threadIdx.x >> 6;
  const int lane = threadIdx.x & 63;
  const int span = blk * 4 + wave;  // 0..M-1
  const int b = span >> 12;
  const int start = span_idx[span * 2 + 0];
  const int end   = span_idx[span * 2 + 1];
  const float inv = 1.0f / (float)(end - start + 1);
  const floatx4* Pb = (const floatx4*)(P + (long)b * L_DIM * D_DIM);
  const floatx4* Pe = Pb + (long)end * 192 + lane;
  floatx4 s[3];
#pragma unroll
  for (int c = 0; c < 3; ++c) s[c] = Pe[c * 64];
  if (start > 0) {  // wave-uniform branch
    const floatx4* Ps = Pb + (long)(start - 1) * 192 + lane;
#pragma unroll
    for (int c = 0; c < 3; ++c) s[c] -= Ps[c * 64];
  }
  short4v* o = (short4v*)(A + (long)span * D_DIM) + lane;
#pragma unroll
  for (int c = 0; c < 3; ++c) {
    short4v v;
#pragma unroll
    for (int e = 0; e < 4; ++e) v[e] = (short)f2bf(s[c][e] * inv);
    o[c * 64] = v;
  }
}

__global__ __launch_bounds__(256)
void prep(const float* __restrict__ W1, ushort_t* __restrict__ W1T,
          const float* __restrict__ W2, ushort_t* __restrict__ W2T,
          const float* __restrict__ P, const int* __restrict__ span_idx,
          ushort_t* __restrict__ A) {
  const int blk = blockIdx.x;
  if (blk < 2304) {
    transpose_body(W1, W1T, D_DIM, DFF_DIM, blk % 24, blk / 24);
  } else if (blk < 4608) {
    const int b = blk - 2304;
    transpose_body(W2, W2T, DFF_DIM, D_DIM, b % 96, b / 96);
  } else {
    span_body(P, span_idx, A, blk - 4608);
  }
}

// ---------------------------------------------------------------------------
// GEMM1 single-barrier 256x256: Hm = relu(A[16384][768] * W1T[3072][768]^T + b1)
// BK=32, nk=24, 8 waves (2M x 4N), wave-tile 128x64 -> 12 ds_read_b128 per
// 32 MFMA per lane per K-tile (0.375 reads/MFMA -- the m201 ratio; R5's
// 64x64 wave-tile was 0.5 and provably LDS-read-bound).
// TRIPLE-buffered LDS (96 KB): tile k reads buf k%3; tile k+2 staged in
// Ph1(k) into buf (k+2)%3 (= (k-1)%3, whose last reads drained before
// BAR(Ph0,k) -- WAR safe). Gate: vmcnt(4) BEFORE Ph1's barrier -- every
// wave confirms its own tile-k+1 loads retired before any wave crosses,
// so Ph0(k+1) reads are RAW-safe; tile k+2's 4 loads stay in flight.
// 2 phases/K-tile: {8 ds_read | BAR | lgkm0 | 16 MFMA} then
// {4 ds_read | stage 4 | vm(4) | BAR | lgkm0 | 16 MFMA}.
// Chunk-XOR swizzle (round-0 verified): LDS slot c holds global chunk
// c ^ (r&3) ^ ((r>>2)&3); fragment coff = (quad^swz(l16))*8 -> 2-way max.
// ---------------------------------------------------------------------------
__global__ __launch_bounds__(512, 2)
void gemm_sb(const ushort_t* __restrict__ A, const ushort_t* __restrict__ Bt,
             const float* __restrict__ bias, ushort_t* __restrict__ C) {
  __shared__ ushort_t As[3][256 * 32];  // 48 KB
  __shared__ ushort_t Bs[3][256 * 32];  // 48 KB

  const int tid  = threadIdx.x;
  const int lane = tid & 63;
  const int l16  = lane & 15;
  const int quad = lane >> 4;
  const int wave = tid >> 6;
  const int wr   = wave >> 2;  // 0..1 (M half, 128 rows)
  const int wc   = wave & 3;   // 0..3 (N quarter, 64 cols)

  const int bm = blockIdx.x;   // 0..63  (fast: consecutive blocks share bn)
  const int bn = blockIdx.y;   // 0..11

  const int K = D_DIM;         // 768
  const int nk = 24;           // 768 / 32

  // staging: seg s (16B) -> row s>>2, slot s&3; global chunk = slot^swz(row)
  const int s0 = tid, s1 = tid + 512;
  const int r0 = s0 >> 2, r1 = s1 >> 2;
  const int c0 = (s0 & 3) ^ (r0 & 3) ^ ((r0 >> 2) & 3);
  const int c1 = (s1 & 3) ^ (r1 & 3) ^ ((r1 >> 2) & 3);
  const ushort_t* gA0 = A + (long)(bm * 256 + r0) * K + c0 * 8;
  const ushort_t* gA1 = A + (long)(bm * 256 + r1) * K + c1 * 8;
  const ushort_t* gB0 = Bt + (long)(bn * 256 + r0) * K + c0 * 8;
  const ushort_t* gB1 = Bt + (long)(bn * 256 + r1) * K + c1 * 8;

  auto STAGE_A = [&](int buf, int kt) {
    const int ko = kt * 32;
    load_lds16(gA0 + ko, &As[buf][0] + s0 * 8);
    load_lds16(gA1 + ko, &As[buf][0] + s1 * 8);
  };
  auto STAGE_B = [&](int buf, int kt) {
    const int ko = kt * 32;
    load_lds16(gB0 + ko, &Bs[buf][0] + s0 * 8);
    load_lds16(gB1 + ko, &Bs[buf][0] + s1 * 8);
  };

  // fragment reads: addr = row*32 + (quad ^ swz(l16))*8 ; swz depends on l16
  const int coff = ((quad ^ (l16 & 3) ^ ((l16 >> 2) & 3))) * 8;
  const int arow0 = (wr * 128 + l16) * 32;
  const int brow0 = (wc * 64 + l16) * 32;

  floatx4 acc[8][4];
#pragma unroll
  for (int i = 0; i < 8; ++i)
#pragma unroll
    for (int j = 0; j < 4; ++j) acc[i][j] = (floatx4)0.0f;

  // prologue: stage tiles 0,1; gate tile 0 (tile 1's 4 stay in flight)
  STAGE_A(0, 0); STAGE_B(0, 0);
  STAGE_A(1, 1); STAGE_B(1, 1);
  WAIT_VM(4);
  BAR();

  short8 af[4], af2[4], bf[4];
  int cur = 0;

  for (int k = 0; k < nk; ++k) {
    const int s2 = (cur + 2 >= 3) ? cur - 1 : cur + 2;  // (k+2)%3
    const ushort_t* Ac = &As[cur][0];
    const ushort_t* Bc = &Bs[cur][0];
    const bool pf = (k + 2 < nk);

    // ---- Ph0: ds af[0..3] + bf[0..3] | BAR | MFMA upper-half (16) --------
#pragma unroll
    for (int i = 0; i < 4; ++i)
      af[i] = *(const short8*)(Ac + arow0 + i * 512 + coff);
#pragma unroll
    for (int j = 0; j < 4; ++j)
      bf[j] = *(const short8*)(Bc + brow0 + j * 512 + coff);
    BAR();
    WAIT_LGKM0();
    __builtin_amdgcn_s_setprio(1);
#pragma unroll
    for (int i = 0; i < 4; ++i)
#pragma unroll
      for (int j = 0; j < 4; ++j)
        acc[i][j] = __builtin_amdgcn_mfma_f32_16x16x32_bf16(af[i], bf[j], acc[i][j], 0, 0, 0);
    __builtin_amdgcn_s_setprio(0);

    // ---- Ph1: ds af2[0..3]; stage tile k+2; gate | BAR | MFMA lower (16) -
#pragma unroll
    for (int i = 0; i < 4; ++i)
      af2[i] = *(const short8*)(Ac + arow0 + (4 + i) * 512 + coff);
    if (pf) {
      STAGE_A(s2, k + 2);
      STAGE_B(s2, k + 2);
      WAIT_VM(4);  // tile k+1 landed (all waves gate before the barrier)
    } else {
      WAIT_VM(0);  // tail drain
    }
    BAR();
    WAIT_LGKM0();
    __builtin_amdgcn_s_setprio(1);
#pragma unroll
    for (int i = 0; i < 4; ++i)
#pragma unroll
      for (int j = 0; j < 4; ++j)
        acc[4 + i][j] = __builtin_amdgcn_mfma_f32_16x16x32_bf16(af2[i], bf[j], acc[4 + i][j], 0, 0, 0);
    __builtin_amdgcn_s_setprio(0);

    cur = (cur + 1 >= 3) ? 0 : cur + 1;
  }

  // epilogue: C/D layout col = l16, row = quad*4 + r ; relu -> bf16
  const long rowbase = (long)bm * 256 + wr * 128 + quad * 4;
  const int  colbase = bn * 256 + wc * 64 + l16;
#pragma unroll
  for (int j = 0; j < 4; ++j) {
    const int col = colbase + j * 16;
    const float bv = bias[col];
#pragma unroll
    for (int i = 0; i < 8; ++i) {
      const long row0 = rowbase + i * 16;
#pragma unroll
      for (int r = 0; r < 4; ++r) {
        float v = acc[i][j][r] + bv;
        v = v > 0.0f ? v : 0.0f;
        C[(row0 + r) * DFF_DIM + col] = f2bf(v);
      }
    }
  }
}

// ---------------------------------------------------------------------------
// GEMM2: round-0 PROVEN kernel, verbatim (111.4 us measured).
// ---------------------------------------------------------------------------
template <int MODE>
__global__ __launch_bounds__(256)
void gemm_bt(const ushort_t* __restrict__ A, const ushort_t* __restrict__ Bt,
             const float* __restrict__ bias, void* __restrict__ Cv,
             int M, int N, int K) {
  __shared__ ushort_t As[2][128 * 32];
  __shared__ ushort_t Bs[2][128 * 32];

  const int tid  = threadIdx.x;
  const int lane = tid & 63;
  const int wave = tid >> 6;
  const int l16  = lane & 15;
  const int quad = lane >> 4;

  const int bm = blockIdx.x;
  const int bn = blockIdx.y;

  const int wm = (wave & 1) * 64;
  const int wn = (wave >> 1) * 64;

  const int swz  = (l16 & 3) ^ ((l16 >> 2) & 3);
  const int coff = (quad ^ swz) * 8;

  floatx4 acc[4][4];
#pragma unroll
  for (int i = 0; i < 4; ++i)
#pragma unroll
    for (int j = 0; j < 4; ++j)
      acc[i][j] = (floatx4)0.0f;

  const int s0 = tid, s1 = tid + 256;
  const int r0 = s0 >> 2, r1 = s1 >> 2;
  const int c0 = (s0 & 3) ^ (r0 & 3) ^ ((r0 >> 2) & 3);
  const int c1 = (s1 & 3) ^ (r1 & 3) ^ ((r1 >> 2) & 3);
  const ushort_t* gA0 = A + (long)(bm * 128 + r0) * K + c0 * 8;
  const ushort_t* gA1 = A + (long)(bm * 128 + r1) * K + c1 * 8;
  const ushort_t* gB0 = Bt + (long)(bn * 128 + r0) * K + c0 * 8;
  const ushort_t* gB1 = Bt + (long)(bn * 128 + r1) * K + c1 * 8;

  const int nk = K >> 5;

  load_lds16(gA0, &As[0][0] + s0 * 8);
  load_lds16(gA1, &As[0][0] + s1 * 8);
  load_lds16(gB0, &Bs[0][0] + s0 * 8);
  load_lds16(gB1, &Bs[0][0] + s1 * 8);

  for (int k = 0; k < nk; ++k) {
    const int cur = k & 1;
    const int nxt = cur ^ 1;
    __syncthreads();

    if (k + 1 < nk) {
      const int off = (k + 1) * 32;
      load_lds16(gA0 + off, &As[nxt][0] + s0 * 8);
      load_lds16(gA1 + off, &As[nxt][0] + s1 * 8);
      load_lds16(gB0 + off, &Bs[nxt][0] + s0 * 8);
      load_lds16(gB1 + off, &Bs[nxt][0] + s1 * 8);
    }

    short8 af[4], bf[4];
#pragma unroll
    for (int i = 0; i < 4; ++i)
      af[i] = *(const short8*)(&As[cur][0] + (wm + i * 16 + l16) * 32 + coff);
#pragma unroll
    for (int j = 0; j < 4; ++j)
      bf[j] = *(const short8*)(&Bs[cur][0] + (wn + j * 16 + l16) * 32 + coff);
#pragma unroll
    for (int i = 0; i < 4; ++i)
#pragma unroll
      for (int j = 0; j < 4; ++j)
        acc[i][j] = __builtin_amdgcn_mfma_f32_16x16x32_bf16(af[i], bf[j], acc[i][j], 0, 0, 0);
  }

#pragma unroll
  for (int i = 0; i < 4; ++i) {
#pragma unroll
    for (int j = 0; j < 4; ++j) {
      const int col = bn * 128 + wn + j * 16 + l16;
      const float bv = bias[col];
      const int row0 = bm * 128 + wm + i * 16 + quad * 4;
#pragma unroll
      for (int r = 0; r < 4; ++r) {
        float v = acc[i][j][r] + bv;
        if (MODE == 0) {
          v = v > 0.0f ? v : 0.0f;
          ((ushort_t*)Cv)[(long)(row0 + r) * N + col] = f2bf(v);
        } else {
          ((float*)Cv)[(long)(row0 + r) * N + col] = v;
        }
      }
    }
  }
}

extern "C" void kernel_launch(void* const* d_in, const int* in_sizes, int n_in,
                              void* d_out, int out_size, void* d_ws, size_t ws_size,
                              hipStream_t stream) {
  const float* h        = (const float*)d_in[0];
  const int*   span_idx = (const int*)d_in[1];
  const float* W1       = (const float*)d_in[2];
  const float* b1       = (const float*)d_in[3];
  const float* W2       = (const float*)d_in[4];
  const float* b2       = (const float*)d_in[5];
  float* out = (float*)d_out;

  // workspace layout (bf16 elements): A | W1T | W2T | Hmid
  ushort_t* A   = (ushort_t*)d_ws;
  ushort_t* W1T = A + (size_t)M_DIM * D_DIM;
  ushort_t* W2T = W1T + (size_t)DFF_DIM * D_DIM;
  ushort_t* Hm  = W2T + (size_t)D_DIM * DFF_DIM;

  // prefix table P aliases Hmid space (P is dead before GEMM1 writes Hm)
  float* P = (float*)Hm;  // 4*512*768*4 = 6.3 MB << Hm's 100.7 MB

  // 1) prefix sums over L (for O(1) span means)
  scan<<<12, 256, 0, stream>>>(h, P);

  // 2) fused prep: weight transposes + span means from P
  prep<<<2304 + 2304 + M_DIM / 4, 256, 0, stream>>>(W1, W1T, W2, W2T, P, span_idx, A);

  // 3) GEMM1: 256x256 single-barrier pipeline (64 bm x 12 bn, bm-fast)
  gemm_sb<<<dim3(64, 12), 512, 0, stream>>>(A, W1T, b1, Hm);

  // 4) GEMM2: Hmid (M x DFF) * W2 (DFF x D) + b2 -> out fp32  [proven]
  gemm_bt<1><<<dim3(M_DIM / 128, D_DIM / 128), 256, 0, stream>>>(
      Hm, W2T, b2, out, M_DIM, D_DIM, DFF_DIM);
}